// Round 10
// baseline (249.207 us; speedup 1.0000x reference)
//
#include <hip/hip_runtime.h>

// MHA fwd: B=4 N=2048 E=768 H=8 d=96. fp32 inputs (detected) -> canonical bf16.
// R10: attn v3 — 4 waves x 32 q-rows (two 16-row fragment sets per wave): each
// Ks/Vts B-fragment read feeds 2 MFMAs => LDS B-frag traffic halved (attn was
// LDS-BW bound: 26KB/wave-tile x 16 waves/CU). Cheap P->bf16 (half-up round).
// GEMMs/convert/detect byte-identical to R9.

#define E_DIM 768
#define N_HEAD 8
#define D_HEAD 96
#define B_SZ 4
#define N_SEQ 2048
#define BN (B_SZ * N_SEQ)   // 8192 rows

typedef unsigned short u16;
typedef __attribute__((ext_vector_type(8))) unsigned short u16x8;
typedef __attribute__((ext_vector_type(4))) unsigned short u16x4;
typedef __attribute__((ext_vector_type(8))) short s16x8;   // bf16 MFMA A/B frag
typedef __attribute__((ext_vector_type(4))) float f32x4;   // MFMA C/D frag

#define SZ_X   ((size_t)BN * E_DIM)          // 6291456
#define SZ_W   ((size_t)E_DIM * E_DIM)       // 589824
#define SZ_B   ((size_t)E_DIM)               // 768
#define N_CONV (SZ_X + 4 * SZ_W + 4 * SZ_B)  // 8653824

__device__ __forceinline__ float bf2f(u16 u) {
    union { unsigned u; float f; } c; c.u = ((unsigned)u) << 16; return c.f;
}
__device__ __forceinline__ u16 f2bf(float f) {
    union { float f; unsigned u; } c; c.f = f;
    unsigned r = c.u + 0x7FFFu + ((c.u >> 16) & 1u);  // round-nearest-even
    return (u16)(r >> 16);
}
__device__ __forceinline__ u16 f2bf_fast(float f) {   // half-up round, 2 ops
    union { float f; unsigned u; } c; c.f = f;
    return (u16)((c.u + 0x8000u) >> 16);
}
// async global->LDS 16B: lane i lands at ldsbase + i*16 (wave-uniform base!)
__device__ __forceinline__ void gl_lds16(const u16* g, u16* l) {
    __builtin_amdgcn_global_load_lds(
        (const __attribute__((address_space(1))) unsigned int*)g,
        (__attribute__((address_space(3))) unsigned int*)l, 16, 0, 0);
}

// ---- dtype detection: fp32 data read as u16 pairs -> wild exponents on even u16s.
__global__ void detect_dtype(const void* __restrict__ x, int* __restrict__ flag) {
    __shared__ int cnt;
    if (threadIdx.x == 0) cnt = 0;
    __syncthreads();
    const u16* p = (const u16*)x;
    u16 u = p[(size_t)threadIdx.x * 2];
    int ef = (u >> 7) & 0xFF;
    int insane = (ef < 96 || ef > 159) ? 1 : 0;
    atomicAdd(&cnt, insane);
    __syncthreads();
    if (threadIdx.x == 0) *flag = (cnt > 128) ? 1 : 0;   // 1 = fp32 inputs
}

// ---- convert: 8 elems/thread, vectorized. Region boundaries all %8==0.
__global__ __launch_bounds__(256) void convert8(
    const int* __restrict__ flag,
    const void* __restrict__ x,
    const void* __restrict__ wq, const void* __restrict__ wk,
    const void* __restrict__ wv, const void* __restrict__ wo,
    const void* __restrict__ bq, const void* __restrict__ bk,
    const void* __restrict__ bv, const void* __restrict__ bo,
    u16* __restrict__ dst)
{
    size_t i = ((size_t)blockIdx.x * 256 + threadIdx.x) * 8;
    if (i >= N_CONV) return;
    const int f32 = *flag;
    size_t r = i;
    const void* s;
    if (r < SZ_X) { s = x; }
    else { r -= SZ_X;
      if (r < SZ_W) { s = wq; }
      else { r -= SZ_W;
        if (r < SZ_W) { s = wk; }
        else { r -= SZ_W;
          if (r < SZ_W) { s = wv; }
          else { r -= SZ_W;
            if (r < SZ_W) { s = wo; }
            else { r -= SZ_W;
              if (r < SZ_B) { s = bq; }
              else { r -= SZ_B;
                if (r < SZ_B) { s = bk; }
                else { r -= SZ_B;
                  if (r < SZ_B) { s = bv; }
                  else { r -= SZ_B; s = bo; }
                }
              }
            }
          }
        }
      }
    }
    u16x8 o;
    if (f32) {
        float4 a = ((const float4*)((const float*)s + r))[0];
        float4 b = ((const float4*)((const float*)s + r))[1];
        o[0] = f2bf(a.x); o[1] = f2bf(a.y); o[2] = f2bf(a.z); o[3] = f2bf(a.w);
        o[4] = f2bf(b.x); o[5] = f2bf(b.y); o[6] = f2bf(b.z); o[7] = f2bf(b.w);
    } else {
        o = *(const u16x8*)((const u16*)s + r);
    }
    *(u16x8*)(dst + i) = o;
}

// ==== MFMA GEMM core: 128x128 tile, BK=64, DOUBLE-BUFFERED (single barrier/iter).
// XOR chunk-swizzle: phys chunk = log chunk ^ (row&7) -> ~2-way frag reads.
#define GBK 64
#define GBUF (128 * GBK)          // elems per operand per buffer (8192)

#define GEMM_STAGE(Ab, Wb, kt, As_, Bs_)                                        \
    {                                                                           \
        const int kt_ = (kt);                                                   \
        _Pragma("unroll")                                                       \
        for (int j = 0; j < 4; j++) {                                           \
            int st = wave * 4 + j;                                              \
            int row = st * 8 + (lane >> 3);                                     \
            int cl = (lane & 7) ^ ((lane >> 3) & 7);                            \
            gl_lds16(Ab + (size_t)row * E_DIM + kt_ + cl * 8, (As_) + st * 512);\
            gl_lds16(Wb + (size_t)row * E_DIM + kt_ + cl * 8, (Bs_) + st * 512);\
        }                                                                       \
    }

#define GEMM_COMPUTE(As_, Bs_)                                                  \
    {                                                                           \
        _Pragma("unroll")                                                       \
        for (int s = 0; s < 2; s++) {                                           \
            s16x8 af[4], bf[4];                                                 \
            _Pragma("unroll")                                                   \
            for (int mi = 0; mi < 4; mi++) {                                    \
                int row = wm * 64 + mi * 16 + l16;                              \
                af[mi] = *(const s16x8*)&(As_)[row * GBK + ((s * 4 + q4) ^ (l16 & 7)) * 8]; \
            }                                                                   \
            _Pragma("unroll")                                                   \
            for (int ni = 0; ni < 4; ni++) {                                    \
                int row = wn * 64 + ni * 16 + l16;                              \
                bf[ni] = *(const s16x8*)&(Bs_)[row * GBK + ((s * 4 + q4) ^ (l16 & 7)) * 8]; \
            }                                                                   \
            _Pragma("unroll")                                                   \
            for (int mi = 0; mi < 4; mi++)                                      \
                _Pragma("unroll")                                               \
                for (int ni = 0; ni < 4; ni++)                                  \
                    acc[mi][ni] = __builtin_amdgcn_mfma_f32_16x16x32_bf16(      \
                        af[mi], bf[ni], acc[mi][ni], 0, 0, 0);                  \
        }                                                                       \
    }

#define GEMM_KLOOP_DB(Ab, Wb)                                                   \
    GEMM_STAGE(Ab, Wb, 0, smem, smem + GBUF)                                    \
    for (int it = 0; it < 12; it++) {                                           \
        __syncthreads();                                                        \
        if (it < 11) {                                                          \
            u16* An = smem + ((it + 1) & 1) * 2 * GBUF;                         \
            GEMM_STAGE(Ab, Wb, (it + 1) * GBK, An, An + GBUF)                   \
        }                                                                       \
        u16* Ac = smem + (it & 1) * 2 * GBUF;                                   \
        GEMM_COMPUTE(Ac, Ac + GBUF)                                             \
    }

// Fused QKV GEMM: W = stacked Wq,Wk,Wv [2304][768].
__global__ __launch_bounds__(256) void gemm_mfma_qkv(
    const u16* __restrict__ A, const u16* __restrict__ W,
    const u16* __restrict__ bias, u16* __restrict__ C, u16* __restrict__ Vt)
{
    __shared__ u16 smem[4 * GBUF];   // 64 KB
    const int tid = threadIdx.x;
    const int wave = tid >> 6, lane = tid & 63;
    const int q4 = lane >> 4, l16 = lane & 15;
    const int wm = wave & 1, wn = wave >> 1;
    const int bm = blockIdx.x, bn = blockIdx.y;

    f32x4 acc[4][4];
    #pragma unroll
    for (int i = 0; i < 4; i++)
        #pragma unroll
        for (int j = 0; j < 4; j++) acc[i][j] = (f32x4){0.f, 0.f, 0.f, 0.f};

    const u16* Ab = A + (size_t)(bm * 128) * E_DIM;
    const u16* Wb = W + (size_t)(bn * 128) * E_DIM;
    GEMM_KLOOP_DB(Ab, Wb)

    if (bn < 12) {
        u16* Cb = smem;
        u16* Cw = C + (size_t)(bn / 6) * SZ_X;
        const int nc0 = (bn % 6) * 128;
        const int row = tid >> 3, seg = (tid & 7) * 16;
        #pragma unroll
        for (int mi = 0; mi < 4; mi++) {
            __syncthreads();
            #pragma unroll
            for (int ni = 0; ni < 4; ni++) {
                int n_l = wn * 64 + ni * 16 + l16;
                float bi = bf2f(bias[bn * 128 + n_l]);
                #pragma unroll
                for (int r = 0; r < 4; r++)
                    Cb[(wm * 16 + q4 * 4 + r) * 136 + n_l] = f2bf(acc[mi][ni][r] + bi);
            }
            __syncthreads();
            int mrow = bm * 128 + (row >> 4) * 64 + mi * 16 + (row & 15);
            *(u16x8*)(Cw + (size_t)mrow * E_DIM + nc0 + seg)     = *(const u16x8*)&Cb[row * 136 + seg];
            *(u16x8*)(Cw + (size_t)mrow * E_DIM + nc0 + seg + 8) = *(const u16x8*)&Cb[row * 136 + seg + 8];
        }
    } else {
        u16* Cb = smem;
        const int bnv = bn - 12;
        const int b = bm >> 4;
        const int n_l = tid >> 1, m0 = (tid & 1) * 16;
        const size_t vrow = (size_t)(b * 768 + bnv * 128 + n_l);
        #pragma unroll
        for (int mi = 0; mi < 4; mi++) {
            __syncthreads();
            #pragma unroll
            for (int ni = 0; ni < 4; ni++) {
                int nl = wn * 64 + ni * 16 + l16;
                float bi = bf2f(bias[bn * 128 + nl]);
                #pragma unroll
                for (int r = 0; r < 4; r++)
                    Cb[nl * 40 + wm * 16 + q4 * 4 + r] = f2bf(acc[mi][ni][r] + bi);
            }
            __syncthreads();
            int seq0 = (bm & 15) * 128 + (tid & 1) * 64 + mi * 16;
            *(u16x8*)(Vt + vrow * N_SEQ + seq0)     = *(const u16x8*)&Cb[n_l * 40 + m0];
            *(u16x8*)(Vt + vrow * N_SEQ + seq0 + 8) = *(const u16x8*)&Cb[n_l * 40 + m0 + 8];
        }
    }
}

// Output GEMM: W = Wo [768][768]; fp32-or-bf16 store via float bounce (aliased).
__global__ __launch_bounds__(256) void gemm_mfma_out(
    const u16* __restrict__ A, const u16* __restrict__ W,
    const u16* __restrict__ bias, void* __restrict__ C,
    const int* __restrict__ flag)
{
    __shared__ u16 smem[4 * GBUF];
    const int tid = threadIdx.x;
    const int wave = tid >> 6, lane = tid & 63;
    const int q4 = lane >> 4, l16 = lane & 15;
    const int wm = wave & 1, wn = wave >> 1;
    const int bm = blockIdx.x, bn = blockIdx.y;

    f32x4 acc[4][4];
    #pragma unroll
    for (int i = 0; i < 4; i++)
        #pragma unroll
        for (int j = 0; j < 4; j++) acc[i][j] = (f32x4){0.f, 0.f, 0.f, 0.f};

    const u16* Ab = A + (size_t)(bm * 128) * E_DIM;
    const u16* Wb = W + (size_t)(bn * 128) * E_DIM;
    GEMM_KLOOP_DB(Ab, Wb)

    float* Cbf = (float*)smem;
    const int f32 = *flag;
    const int row = tid >> 3, seg = (tid & 7) * 16;
    #pragma unroll
    for (int mi = 0; mi < 4; mi++) {
        __syncthreads();
        #pragma unroll
        for (int ni = 0; ni < 4; ni++) {
            int n_l = wn * 64 + ni * 16 + l16;
            float bi = bf2f(bias[bn * 128 + n_l]);
            #pragma unroll
            for (int r = 0; r < 4; r++)
                Cbf[(wm * 16 + q4 * 4 + r) * 132 + n_l] = acc[mi][ni][r] + bi;
        }
        __syncthreads();
        int mrow = bm * 128 + (row >> 4) * 64 + mi * 16 + (row & 15);
        if (f32) {
            #pragma unroll
            for (int c = 0; c < 4; c++)
                *(float4*)((float*)C + (size_t)mrow * E_DIM + bn * 128 + seg + c * 4) =
                    *(const float4*)&Cbf[row * 132 + seg + c * 4];
        } else {
            u16x8 o0, o1;
            #pragma unroll
            for (int c = 0; c < 8; c++) {
                o0[c] = f2bf(Cbf[row * 132 + seg + c]);
                o1[c] = f2bf(Cbf[row * 132 + seg + 8 + c]);
            }
            *(u16x8*)((u16*)C + (size_t)mrow * E_DIM + bn * 128 + seg)     = o0;
            *(u16x8*)((u16*)C + (size_t)mrow * E_DIM + bn * 128 + seg + 8) = o1;
        }
    }
}

// ---- MFMA flash attention v3: 4 waves x 32 q-rows (2 fragment sets/wave),
// dbuf K/V, 1 barrier/tile, 64 KB LDS. Each B-frag read feeds 2 MFMAs.
#define KT 64

#define ATTN_STAGE(kt, bb)                                                       \
    {                                                                            \
        const int kt_ = (kt); const int bb_ = (bb);                              \
        _Pragma("unroll")                                                        \
        for (int ii = 0; ii < 6; ii++) {                                         \
            int st = wave + 4 * ii;                                              \
            if (st < 12) {                                                       \
                int plane = st >> 2, sub = st & 3;                               \
                int cip = sub * 64 + lane;                                       \
                int r = cip >> 2;                                                \
                int cs2 = (cip & 3) ^ ((r >> 1) & 3);                            \
                gl_lds16(K + (size_t)(b * N_SEQ + kt_ + r) * E_DIM + h * D_HEAD + plane * 32 + cs2 * 8, \
                         &Ks[bb_][plane * 2048 + sub * 512]);                    \
            } else {                                                             \
                int j = st - 12;                                                 \
                int plane = j / 6, sub = j - plane * 6;                          \
                int cip = sub * 64 + lane;                                       \
                int r = cip >> 2;                                                \
                int cs2 = (cip & 3) ^ ((r >> 1) & 3);                            \
                gl_lds16(Vt + (size_t)((b * N_HEAD + h) * D_HEAD + r) * N_SEQ + kt_ + plane * 32 + cs2 * 8, \
                         &Vts[bb_][plane * 3072 + sub * 512]);                   \
            }                                                                    \
        }                                                                        \
    }

__global__ __launch_bounds__(256) void attn_mfma3(
    const u16* __restrict__ Q, const u16* __restrict__ K,
    const u16* __restrict__ Vt, u16* __restrict__ O)
{
    __shared__ u16 Ks[2][3 * 64 * 32];    // 24576 B
    __shared__ u16 Vts[2][2 * 96 * 32];   // 24576 B
    __shared__ u16 Ps[4 * 32 * 64];       // 16384 B   total = 65536 B exactly

    const int tid = threadIdx.x;
    const int wave = tid >> 6, lane = tid & 63;
    const int q4 = lane >> 4, l16 = lane & 15;
    const int swz = (l16 >> 1) & 3;
    const int b = blockIdx.z, h = blockIdx.y, qb = blockIdx.x;

    const float SCL2 = 0.10206207261596577f * 1.4426950408889634f;  // 1/sqrt(96)*log2(e)

    // Two 16-row Q fragment sets per wave: rows qb*128 + wave*32 + rs*16 + l16.
    s16x8 qf[2][3];
    #pragma unroll
    for (int rs = 0; rs < 2; rs++) {
        const int qrow = qb * 128 + wave * 32 + rs * 16 + l16;
        const u16* qptr = Q + (size_t)(b * N_SEQ + qrow) * E_DIM + h * D_HEAD;
        #pragma unroll
        for (int ks = 0; ks < 3; ks++) {
            u16x8 raw = *(const u16x8*)(qptr + ks * 32 + q4 * 8);
            #pragma unroll
            for (int j = 0; j < 8; j++)
                qf[rs][ks][j] = (short)f2bf(bf2f(raw[j]) * SCL2);
        }
    }

    f32x4 of[2][6];
    #pragma unroll
    for (int rs = 0; rs < 2; rs++)
        #pragma unroll
        for (int i = 0; i < 6; i++) of[rs][i] = (f32x4){0.f, 0.f, 0.f, 0.f};
    float l_r[2][4] = {{0.f, 0.f, 0.f, 0.f}, {0.f, 0.f, 0.f, 0.f}};

    u16* psw = Ps + wave * 32 * 64;   // wave-private P [32 rows][64], swizzled

    ATTN_STAGE(0, 0)
    for (int t = 0; t < N_SEQ / KT; t++) {
        __syncthreads();                 // drains tile t's DMA (issued 1 phase ago)
        if (t < N_SEQ / KT - 1) ATTN_STAGE((t + 1) * KT, (t + 1) & 1)
        const int cb = t & 1;

        // S = Q.K^T : one B-frag read feeds both rowsets.
        f32x4 sf[2][4];
        #pragma unroll
        for (int rs = 0; rs < 2; rs++)
            #pragma unroll
            for (int i = 0; i < 4; i++) sf[rs][i] = (f32x4){0.f, 0.f, 0.f, 0.f};
        #pragma unroll
        for (int nt = 0; nt < 4; nt++)
            #pragma unroll
            for (int ks = 0; ks < 3; ks++) {
                s16x8 bfr = *(const s16x8*)&Ks[cb][ks * 2048 + (nt * 16 + l16) * 32 + ((q4 ^ swz) << 3)];
                #pragma unroll
                for (int rs = 0; rs < 2; rs++)
                    sf[rs][nt] = __builtin_amdgcn_mfma_f32_16x16x32_bf16(qf[rs][ks], bfr, sf[rs][nt], 0, 0, 0);
            }

        // p = 2^s', accumulate row-sums, store P swizzled.
        #pragma unroll
        for (int rs = 0; rs < 2; rs++)
            #pragma unroll
            for (int nt = 0; nt < 4; nt++)
                #pragma unroll
                for (int r = 0; r < 4; r++) {
                    float pv = exp2f(sf[rs][nt][r]);
                    l_r[rs][r] += pv;
                    int prow = rs * 16 + q4 * 4 + r;
                    psw[prow * 64 + (((nt * 2 + (l16 >> 3)) ^ (prow & 7)) << 3) + (l16 & 7)] = f2bf_fast(pv);
                }

        // O += P.V : one V B-frag read feeds both rowsets.
        #pragma unroll
        for (int ks2 = 0; ks2 < 2; ks2++) {
            s16x8 afr[2];
            #pragma unroll
            for (int rs = 0; rs < 2; rs++)
                afr[rs] = *(const s16x8*)&psw[(rs * 16 + l16) * 64 + (((ks2 * 4 + q4) ^ (l16 & 7)) << 3)];
            #pragma unroll
            for (int nt = 0; nt < 6; nt++) {
                s16x8 bfr = *(const s16x8*)&Vts[cb][ks2 * 3072 + (nt * 16 + l16) * 32 + ((q4 ^ swz) << 3)];
                #pragma unroll
                for (int rs = 0; rs < 2; rs++)
                    of[rs][nt] = __builtin_amdgcn_mfma_f32_16x16x32_bf16(afr[rs], bfr, of[rs][nt], 0, 0, 0);
            }
        }
    }

    // row-sum reduce, normalize, store (per rowset).
    #pragma unroll
    for (int rs = 0; rs < 2; rs++) {
        float linv[4];
        #pragma unroll
        for (int r = 0; r < 4; r++) {
            float l = l_r[rs][r];
            #pragma unroll
            for (int off = 1; off < 16; off <<= 1)
                l += __shfl_xor(l, off, 64);
            linv[r] = 1.0f / l;
        }
        u16* optr = O + (size_t)(b * N_SEQ + qb * 128 + wave * 32 + rs * 16) * E_DIM + h * D_HEAD;
        #pragma unroll
        for (int nt = 0; nt < 6; nt++)
            #pragma unroll
            for (int r = 0; r < 4; r++)
                optr[(size_t)(q4 * 4 + r) * E_DIM + nt * 16 + l16] = f2bf(of[rs][nt][r] * linv[r]);
    }
}

extern "C" void kernel_launch(void* const* d_in, const int* in_sizes, int n_in,
                              void* d_out, int out_size, void* d_ws, size_t ws_size,
                              hipStream_t stream) {
    (void)in_sizes; (void)n_in; (void)out_size; (void)ws_size;
    const void* x  = d_in[0];
    const void* Wq = d_in[1]; const void* bq = d_in[2];
    const void* Wk = d_in[3]; const void* bk = d_in[4];
    const void* Wv = d_in[5]; const void* bv = d_in[6];
    const void* Wo = d_in[7]; const void* bo = d_in[8];

    int* flag = (int*)d_ws;
    u16* base = (u16*)d_ws + 8;
    u16* xb  = base;
    u16* wqb = xb  + SZ_X;       // Wq,Wk,Wv contiguous => [2304][768]
    u16* wob = wqb + 3 * SZ_W;
    u16* bqb = wob + SZ_W;       // bq,bk,bv contiguous => [2304]
    u16* bob = bqb + 3 * SZ_B;
    u16* q_ws = bob + SZ_B;      // q,k contiguous [2][8192][768]
    u16* k_ws = q_ws + SZ_X;
    u16* vt_ws = k_ws + SZ_X;    // V^T [B*768][2048]
    u16* o_ws = vt_ws + SZ_X;

    detect_dtype<<<1, 256, 0, stream>>>(x, flag);
    convert8<<<(int)((N_CONV / 8 + 255) / 256), 256, 0, stream>>>(
        flag, x, Wq, Wk, Wv, Wo, bq, bk, bv, bo, base);

    gemm_mfma_qkv<<<dim3(BN / 128, 2304 / 128), 256, 0, stream>>>(
        xb, wqb, bqb, q_ws, vt_ws);

    attn_mfma3<<<dim3(N_SEQ / 128, N_HEAD, B_SZ), 256, 0, stream>>>(
        q_ws, k_ws, vt_ws, o_ws);

    gemm_mfma_out<<<dim3(BN / 128, E_DIM / 128), 256, 0, stream>>>(
        o_ws, wob, bob, d_out, flag);
}